// Round 1
// baseline (705.814 us; speedup 1.0000x reference)
//
#include <hip/hip_runtime.h>
#include <hip/hip_cooperative_groups.h>

// MaskedNormalize: x (16, 4, 1024, 1024) fp32. valid = x != 0.
// out = valid ? (x - mean) / (sqrt(var) + eps) : 0, per-sample masked stats.
// Masked-out entries are exactly 0 -> contribute nothing to S1/S2; m2 == 0 analytically.
//
// SINGLE cooperative dispatch: phase 1 per-block partials -> grid.sync() ->
// every block redundantly reduces its own sample's 64 partials (1.5 KB, L2-cheap,
// avoids a second sync) -> phase 2 normalizes the block's own slice (x L3-resident),
// nontemporal stores so out doesn't evict x.
//
// 1024 blocks x 256 threads = 4 blocks/CU at __launch_bounds__(256,4): co-residency
// guaranteed for grid sync; 16 waves/CU with 4-deep float4 unroll = ~64 KiB in
// flight per CU, far above the ~10 KiB needed to cover ~900-cycle HBM latency.
// Partials cross XCDs: agent-scope release store / acquire load (per-XCD L2s are
// not coherent; a plain load after grid.sync could hit a stale line from a prior
// iteration).

#define EPS 1e-5

typedef float v4f __attribute__((ext_vector_type(4)));   // native vec for nontemporal store

constexpr int B              = 16;
constexpr int VEC_PER_SAMPLE = 1 << 20;                  // float4 per sample
constexpr int THREADS        = 256;
constexpr int BLOCKS_PS      = 64;                       // blocks per sample
constexpr int BLOCKS         = B * BLOCKS_PS;            // 1024 = 256 CU * 4
constexpr int VPT            = VEC_PER_SAMPLE / (BLOCKS_PS * THREADS);  // 64 float4/thread

__global__ __launch_bounds__(THREADS, 4)
void fused_masked_norm(const float4* __restrict__ x, v4f* __restrict__ out,
                       double* __restrict__ part) {
    const int sample = blockIdx.x / BLOCKS_PS;
    const int blk    = blockIdx.x % BLOCKS_PS;
    const size_t base = (size_t)sample * VEC_PER_SAMPLE
                      + (size_t)blk * (THREADS * VPT);
    const float4* xs = x + base;

    // ---- phase 1: per-block partial {sum, sumsq, count} ----
    // fp32 accumulation in 4 independent chains (64 floats/chain -> ~4e-6 rel),
    // double only for cross-lane combination.
    float s1[4] = {0.f, 0.f, 0.f, 0.f};
    float s2[4] = {0.f, 0.f, 0.f, 0.f};
    int   cn[4] = {0, 0, 0, 0};

    for (int k = 0; k < VPT; k += 4) {
        #pragma unroll
        for (int u = 0; u < 4; ++u) {
            float4 v = xs[(k + u) * THREADS + threadIdx.x];
            s1[u] += (v.x + v.y) + (v.z + v.w);
            s2[u] += v.x * v.x;
            s2[u] += v.y * v.y;
            s2[u] += v.z * v.z;
            s2[u] += v.w * v.w;
            cn[u] += (v.x != 0.0f) + (v.y != 0.0f) + (v.z != 0.0f) + (v.w != 0.0f);
        }
    }

    double d1 = ((double)s1[0] + s1[1]) + ((double)s1[2] + s1[3]);
    double d2 = ((double)s2[0] + s2[1]) + ((double)s2[2] + s2[3]);
    int    ct = (cn[0] + cn[1]) + (cn[2] + cn[3]);

    #pragma unroll
    for (int off = 32; off > 0; off >>= 1) {
        d1 += __shfl_down(d1, off);
        d2 += __shfl_down(d2, off);
        ct += __shfl_down(ct, off);
    }

    __shared__ double L1[4], L2[4];
    __shared__ int    LC[4];
    const int wave = threadIdx.x >> 6;
    if ((threadIdx.x & 63) == 0) { L1[wave] = d1; L2[wave] = d2; LC[wave] = ct; }
    __syncthreads();
    if (threadIdx.x == 0) {
        double t1 = (L1[0] + L1[1]) + (L1[2] + L1[3]);
        double t2 = (L2[0] + L2[1]) + (L2[2] + L2[3]);
        double tc = (double)((LC[0] + LC[1]) + (LC[2] + LC[3]));
        // agent-scope release: publish past this XCD's L2
        __hip_atomic_store(&part[(size_t)blockIdx.x * 3 + 0], t1,
                           __ATOMIC_RELEASE, __HIP_MEMORY_SCOPE_AGENT);
        __hip_atomic_store(&part[(size_t)blockIdx.x * 3 + 1], t2,
                           __ATOMIC_RELEASE, __HIP_MEMORY_SCOPE_AGENT);
        __hip_atomic_store(&part[(size_t)blockIdx.x * 3 + 2], tc,
                           __ATOMIC_RELEASE, __HIP_MEMORY_SCOPE_AGENT);
    }

    cooperative_groups::this_grid().sync();

    // ---- finalize (redundant per block): reduce own sample's 64 partials ----
    __shared__ float SMEAN, SINV;
    if (threadIdx.x < 64) {
        const size_t p = ((size_t)sample * BLOCKS_PS + threadIdx.x) * 3;
        // agent-scope acquire: never serve a stale line from this XCD's L2
        double e1 = __hip_atomic_load(&part[p + 0], __ATOMIC_ACQUIRE, __HIP_MEMORY_SCOPE_AGENT);
        double e2 = __hip_atomic_load(&part[p + 1], __ATOMIC_ACQUIRE, __HIP_MEMORY_SCOPE_AGENT);
        double ec = __hip_atomic_load(&part[p + 2], __ATOMIC_ACQUIRE, __HIP_MEMORY_SCOPE_AGENT);
        #pragma unroll
        for (int off = 32; off > 0; off >>= 1) {
            e1 += __shfl_down(e1, off);
            e2 += __shfl_down(e2, off);
            ec += __shfl_down(ec, off);
        }
        if (threadIdx.x == 0) {
            double n    = ec;
            double mean = e1 / n;
            double var  = (e2 - e1 * e1 / n) / (n - 1.0);
            SMEAN = (float)mean;
            SINV  = (float)(1.0 / (sqrt(var) + EPS));
        }
    }
    __syncthreads();
    const float mean = SMEAN;
    const float inv  = SINV;

    // ---- phase 2: normalize own slice (reads mostly L3-resident) ----
    for (int k = 0; k < VPT; k += 4) {
        #pragma unroll
        for (int u = 0; u < 4; ++u) {
            const size_t idx = base + (size_t)(k + u) * THREADS + threadIdx.x;
            float4 v = x[idx];
            v4f o;
            o.x = (v.x != 0.0f) ? (v.x - mean) * inv : 0.0f;
            o.y = (v.y != 0.0f) ? (v.y - mean) * inv : 0.0f;
            o.z = (v.z != 0.0f) ? (v.z - mean) * inv : 0.0f;
            o.w = (v.w != 0.0f) ? (v.w - mean) * inv : 0.0f;
            __builtin_nontemporal_store(o, &out[idx]);
        }
    }
}

extern "C" void kernel_launch(void* const* d_in, const int* in_sizes, int n_in,
                              void* d_out, int out_size, void* d_ws, size_t ws_size,
                              hipStream_t stream) {
    const float4* x    = (const float4*)d_in[0];
    v4f*          out  = (v4f*)d_out;
    double*       part = (double*)d_ws;   // 1024 * 3 doubles = 24 KB

    void* args[] = { (void*)&x, (void*)&out, (void*)&part };
    hipLaunchCooperativeKernel(reinterpret_cast<void*>(fused_masked_norm),
                               dim3(BLOCKS), dim3(THREADS), args, 0, stream);
}

// Round 2
// 473.044 us; speedup vs baseline: 1.4921x; 1.4921x over previous
//
#include <hip/hip_runtime.h>

// MaskedNormalize: x (16, 4, 1024, 1024) fp32. valid = x != 0.
// out = valid ? (x - mean) / (sqrt(var) + eps) : 0, per-sample masked stats.
// Masked-out entries are exactly 0 -> contribute nothing to S1/S2; m2 == 0 analytically.
//
// TWO dispatches (round-1 lesson: persistent coop grid = 407 us all by itself,
// VALUBusy 4% -- block churn streams, persistent waves don't):
//   pass A: per-block partials {s1, s2, cnt} (proven round-0 kernel, ~6 TB/s)
//   pass B: per-wave redundant finalize (128 triples, 3 KB, L2-hot) + normalize.
// Kernel-boundary release/acquire on one stream makes pass A's plain stores
// visible to pass B -- no atomics needed. x (256 MiB) is exactly L3-sized, so
// pass B's re-read is Infinity-Cache-served; nontemporal stores keep it that way.

#define EPS 1e-5

typedef float v4f __attribute__((ext_vector_type(4)));   // native vec for nontemporal store

constexpr int B               = 16;
constexpr int VEC_PER_SAMPLE  = 1 << 20;   // float4 per sample (4 * 1024 * 1024 / 4)
constexpr int RED_BLOCKS_PS   = 128;
constexpr int RED_THREADS     = 256;
constexpr int RED_VPT         = VEC_PER_SAMPLE / (RED_BLOCKS_PS * RED_THREADS);  // 32
constexpr int NORM_THREADS    = 256;
constexpr int NORM_VPT        = 8;
constexpr int NORM_BLOCKS_PS  = VEC_PER_SAMPLE / (NORM_THREADS * NORM_VPT);      // 512

// Pass A: per-block partial {sum, sumsq, count}. fp32 accumulation in 4 independent
// chains (<=128 elems/chain -> ~1e-5 rel error), double for cross-lane reduction.
__global__ __launch_bounds__(RED_THREADS)
void masked_stats_kernel(const float4* __restrict__ x, double* __restrict__ part) {
    const int sample = blockIdx.x / RED_BLOCKS_PS;
    const int blk    = blockIdx.x % RED_BLOCKS_PS;
    const float4* xs = x + (size_t)sample * VEC_PER_SAMPLE
                         + (size_t)blk * (RED_THREADS * RED_VPT);

    float s1[4] = {0.f, 0.f, 0.f, 0.f};
    float s2[4] = {0.f, 0.f, 0.f, 0.f};
    int   cn[4] = {0, 0, 0, 0};

    for (int k = 0; k < RED_VPT; k += 4) {
        #pragma unroll
        for (int u = 0; u < 4; ++u) {
            float4 v = xs[(k + u) * RED_THREADS + threadIdx.x];
            s1[u] += (v.x + v.y) + (v.z + v.w);
            s2[u] += v.x * v.x;
            s2[u] += v.y * v.y;
            s2[u] += v.z * v.z;
            s2[u] += v.w * v.w;
            cn[u] += (v.x != 0.0f) + (v.y != 0.0f) + (v.z != 0.0f) + (v.w != 0.0f);
        }
    }

    double d1 = ((double)s1[0] + s1[1]) + ((double)s1[2] + s1[3]);
    double d2 = ((double)s2[0] + s2[1]) + ((double)s2[2] + s2[3]);
    int    ct = (cn[0] + cn[1]) + (cn[2] + cn[3]);

    #pragma unroll
    for (int off = 32; off > 0; off >>= 1) {
        d1 += __shfl_down(d1, off);
        d2 += __shfl_down(d2, off);
        ct += __shfl_down(ct, off);
    }

    __shared__ double L1[4], L2[4];
    __shared__ int    LC[4];
    const int wave = threadIdx.x >> 6;
    if ((threadIdx.x & 63) == 0) { L1[wave] = d1; L2[wave] = d2; LC[wave] = ct; }
    __syncthreads();
    if (threadIdx.x == 0) {
        double t1 = (L1[0] + L1[1]) + (L1[2] + L1[3]);
        double t2 = (L2[0] + L2[1]) + (L2[2] + L2[3]);
        int    tc = (LC[0] + LC[1]) + (LC[2] + LC[3]);
        part[(size_t)blockIdx.x * 3 + 0] = t1;
        part[(size_t)blockIdx.x * 3 + 1] = t2;
        part[(size_t)blockIdx.x * 3 + 2] = (double)tc;
    }
}

// Pass B: per-wave redundant finalize + normalize.
// x loads are issued FIRST so the 3 KB partial-reduce latency hides under vmcnt.
__global__ __launch_bounds__(NORM_THREADS)
void masked_norm_kernel(const float4* __restrict__ x, v4f* __restrict__ out,
                        const double* __restrict__ part) {
    const int sample = blockIdx.x / NORM_BLOCKS_PS;
    const int blk    = blockIdx.x % NORM_BLOCKS_PS;
    const size_t base = (size_t)sample * VEC_PER_SAMPLE
                      + (size_t)blk * (NORM_THREADS * NORM_VPT);

    // issue all 8 float4 loads up front (independent of the stats reduce)
    float4 v[NORM_VPT];
    #pragma unroll
    for (int u = 0; u < NORM_VPT; ++u)
        v[u] = x[base + (size_t)u * NORM_THREADS + threadIdx.x];

    // redundant per-wave finalize: 128 partial triples for this sample.
    // lane i handles triples i and i+64, then 6-step butterfly.
    const int lane = threadIdx.x & 63;
    const double* ps = part + (size_t)sample * RED_BLOCKS_PS * 3;
    double e1 = ps[(size_t)lane * 3 + 0] + ps[(size_t)(lane + 64) * 3 + 0];
    double e2 = ps[(size_t)lane * 3 + 1] + ps[(size_t)(lane + 64) * 3 + 1];
    double ec = ps[(size_t)lane * 3 + 2] + ps[(size_t)(lane + 64) * 3 + 2];
    #pragma unroll
    for (int off = 32; off > 0; off >>= 1) {
        e1 += __shfl_down(e1, off);
        e2 += __shfl_down(e2, off);
        ec += __shfl_down(ec, off);
    }
    e1 = __shfl(e1, 0);
    e2 = __shfl(e2, 0);
    ec = __shfl(ec, 0);
    const double n     = ec;
    const double meand = e1 / n;
    const double vard  = (e2 - e1 * e1 / n) / (n - 1.0);
    const float  mean  = (float)meand;
    const float  inv   = (float)(1.0 / (sqrt(vard) + EPS));

    #pragma unroll
    for (int u = 0; u < NORM_VPT; ++u) {
        const size_t idx = base + (size_t)u * NORM_THREADS + threadIdx.x;
        v4f o;
        o.x = (v[u].x != 0.0f) ? (v[u].x - mean) * inv : 0.0f;
        o.y = (v[u].y != 0.0f) ? (v[u].y - mean) * inv : 0.0f;
        o.z = (v[u].z != 0.0f) ? (v[u].z - mean) * inv : 0.0f;
        o.w = (v[u].w != 0.0f) ? (v[u].w - mean) * inv : 0.0f;
        __builtin_nontemporal_store(o, &out[idx]);
    }
}

extern "C" void kernel_launch(void* const* d_in, const int* in_sizes, int n_in,
                              void* d_out, int out_size, void* d_ws, size_t ws_size,
                              hipStream_t stream) {
    const float4* x    = (const float4*)d_in[0];
    v4f*          out  = (v4f*)d_out;
    double*       part = (double*)d_ws;   // 2048 * 3 doubles = 48 KB

    masked_stats_kernel<<<B * RED_BLOCKS_PS, RED_THREADS, 0, stream>>>(x, part);
    masked_norm_kernel<<<B * NORM_BLOCKS_PS, NORM_THREADS, 0, stream>>>(x, out, part);
}

// Round 3
// 471.266 us; speedup vs baseline: 1.4977x; 1.0038x over previous
//
#include <hip/hip_runtime.h>

// MaskedNormalize: x (16, 4, 1024, 1024) fp32. valid = x != 0.
// out = valid ? (x - mean) / (sqrt(var) + eps) : 0, per-sample masked stats.
// Masked-out entries are exactly 0 -> contribute nothing to S1/S2; m2 == 0 analytically.
//
// TWO dispatches (round-1 lesson: persistent coop grid = 407 us alone, VALUBusy 4% --
// block churn streams, persistent waves don't):
//   pass A: per-block partials {s1, s2, cnt}; regular loads so x allocates in L3.
//   pass B: per-wave redundant finalize (128 triples, L2-hot, hidden under x-load
//           latency) + normalize.
//
// Round-3 change -- L3 eviction management in pass B. x is exactly 256 MiB = the
// whole Infinity Cache. Forward re-read order means LRU eviction (from out's
// write-allocations) eats the lines JUST AHEAD of the read cursor -> ~0% hits.
//   1. Pass B walks the buffer in REVERSE linear order: freshest-first, evictions
//      consume the far end we read last.
//   2. Pass B x-loads are NONTEMPORAL: each line is read exactly once, so
//      allocate-on-miss is pure pollution of still-needed x lines.
//   3. Stores stay nontemporal (out is never re-read).

#define EPS 1e-5

typedef float v4f __attribute__((ext_vector_type(4)));   // native vec for nt load/store

constexpr int B               = 16;
constexpr int VEC_PER_SAMPLE  = 1 << 20;   // float4 per sample (4 * 1024 * 1024 / 4)
constexpr int RED_BLOCKS_PS   = 128;
constexpr int RED_THREADS     = 256;
constexpr int RED_VPT         = VEC_PER_SAMPLE / (RED_BLOCKS_PS * RED_THREADS);  // 32
constexpr int NORM_THREADS    = 256;
constexpr int NORM_VPT        = 8;
constexpr int NORM_BLOCKS_PS  = VEC_PER_SAMPLE / (NORM_THREADS * NORM_VPT);      // 512

// Pass A: per-block partial {sum, sumsq, count}. fp32 accumulation in 4 independent
// chains (<=128 elems/chain -> ~1e-5 rel error), double for cross-lane reduction.
__global__ __launch_bounds__(RED_THREADS)
void masked_stats_kernel(const float4* __restrict__ x, double* __restrict__ part) {
    const int sample = blockIdx.x / RED_BLOCKS_PS;
    const int blk    = blockIdx.x % RED_BLOCKS_PS;
    const float4* xs = x + (size_t)sample * VEC_PER_SAMPLE
                         + (size_t)blk * (RED_THREADS * RED_VPT);

    float s1[4] = {0.f, 0.f, 0.f, 0.f};
    float s2[4] = {0.f, 0.f, 0.f, 0.f};
    int   cn[4] = {0, 0, 0, 0};

    for (int k = 0; k < RED_VPT; k += 4) {
        #pragma unroll
        for (int u = 0; u < 4; ++u) {
            float4 v = xs[(k + u) * RED_THREADS + threadIdx.x];
            s1[u] += (v.x + v.y) + (v.z + v.w);
            s2[u] += v.x * v.x;
            s2[u] += v.y * v.y;
            s2[u] += v.z * v.z;
            s2[u] += v.w * v.w;
            cn[u] += (v.x != 0.0f) + (v.y != 0.0f) + (v.z != 0.0f) + (v.w != 0.0f);
        }
    }

    double d1 = ((double)s1[0] + s1[1]) + ((double)s1[2] + s1[3]);
    double d2 = ((double)s2[0] + s2[1]) + ((double)s2[2] + s2[3]);
    int    ct = (cn[0] + cn[1]) + (cn[2] + cn[3]);

    #pragma unroll
    for (int off = 32; off > 0; off >>= 1) {
        d1 += __shfl_down(d1, off);
        d2 += __shfl_down(d2, off);
        ct += __shfl_down(ct, off);
    }

    __shared__ double L1[4], L2[4];
    __shared__ int    LC[4];
    const int wave = threadIdx.x >> 6;
    if ((threadIdx.x & 63) == 0) { L1[wave] = d1; L2[wave] = d2; LC[wave] = ct; }
    __syncthreads();
    if (threadIdx.x == 0) {
        double t1 = (L1[0] + L1[1]) + (L1[2] + L1[3]);
        double t2 = (L2[0] + L2[1]) + (L2[2] + L2[3]);
        int    tc = (LC[0] + LC[1]) + (LC[2] + LC[3]);
        part[(size_t)blockIdx.x * 3 + 0] = t1;
        part[(size_t)blockIdx.x * 3 + 1] = t2;
        part[(size_t)blockIdx.x * 3 + 2] = (double)tc;
    }
}

// Pass B: per-wave redundant finalize + normalize, reverse block order, nt loads.
__global__ __launch_bounds__(NORM_THREADS)
void masked_norm_kernel(const v4f* __restrict__ x, v4f* __restrict__ out,
                        const double* __restrict__ part) {
    // reverse linear order: early-dispatched blocks take the END of x (freshest in L3)
    const int rb     = (B * NORM_BLOCKS_PS - 1) - blockIdx.x;
    const int sample = rb / NORM_BLOCKS_PS;
    const int blk    = rb % NORM_BLOCKS_PS;
    const size_t base = (size_t)sample * VEC_PER_SAMPLE
                      + (size_t)blk * (NORM_THREADS * NORM_VPT);

    // issue all 8 float4 loads up front (independent of the stats reduce);
    // nontemporal: read-once data, don't evict still-needed x lines on miss
    v4f v[NORM_VPT];
    #pragma unroll
    for (int u = 0; u < NORM_VPT; ++u)
        v[u] = __builtin_nontemporal_load(&x[base + (size_t)u * NORM_THREADS + threadIdx.x]);

    // redundant per-wave finalize: 128 partial triples for this sample (L2-hot,
    // hidden under the outstanding x loads). lane i takes triples i and i+64.
    const int lane = threadIdx.x & 63;
    const double* ps = part + (size_t)sample * RED_BLOCKS_PS * 3;
    double e1 = ps[(size_t)lane * 3 + 0] + ps[(size_t)(lane + 64) * 3 + 0];
    double e2 = ps[(size_t)lane * 3 + 1] + ps[(size_t)(lane + 64) * 3 + 1];
    double ec = ps[(size_t)lane * 3 + 2] + ps[(size_t)(lane + 64) * 3 + 2];
    #pragma unroll
    for (int off = 32; off > 0; off >>= 1) {
        e1 += __shfl_down(e1, off);
        e2 += __shfl_down(e2, off);
        ec += __shfl_down(ec, off);
    }
    e1 = __shfl(e1, 0);
    e2 = __shfl(e2, 0);
    ec = __shfl(ec, 0);
    const double n     = ec;
    const double meand = e1 / n;
    const double vard  = (e2 - e1 * e1 / n) / (n - 1.0);
    const float  mean  = (float)meand;
    const float  inv   = (float)(1.0 / (sqrt(vard) + EPS));

    #pragma unroll
    for (int u = 0; u < NORM_VPT; ++u) {
        const size_t idx = base + (size_t)u * NORM_THREADS + threadIdx.x;
        v4f o;
        o.x = (v[u].x != 0.0f) ? (v[u].x - mean) * inv : 0.0f;
        o.y = (v[u].y != 0.0f) ? (v[u].y - mean) * inv : 0.0f;
        o.z = (v[u].z != 0.0f) ? (v[u].z - mean) * inv : 0.0f;
        o.w = (v[u].w != 0.0f) ? (v[u].w - mean) * inv : 0.0f;
        __builtin_nontemporal_store(o, &out[idx]);
    }
}

extern "C" void kernel_launch(void* const* d_in, const int* in_sizes, int n_in,
                              void* d_out, int out_size, void* d_ws, size_t ws_size,
                              hipStream_t stream) {
    const float4* x    = (const float4*)d_in[0];
    v4f*          out  = (v4f*)d_out;
    double*       part = (double*)d_ws;   // 2048 * 3 doubles = 48 KB

    masked_stats_kernel<<<B * RED_BLOCKS_PS, RED_THREADS, 0, stream>>>(x, part);
    masked_norm_kernel<<<B * NORM_BLOCKS_PS, NORM_THREADS, 0, stream>>>(
        (const v4f*)x, out, part);
}